// Round 1
// 100.518 us; speedup vs baseline: 1.0368x; 1.0368x over previous
//
#include <hip/hip_runtime.h>

#define B_    16
#define N_    4096
#define S_    1024
#define K_    32
#define DIN_  64
#define DINC_ 67
#define DOUT_ 64
#define ROWS_ (B_ * N_)
#define NCH   128            // 64 proj + 64 xp output columns
#define NP1   (N_ + 1)       // cmb rows per batch: sentinel row 0 + N rows
#define NTILE 28             // nonzero weight tiles (s0:8, s1:8, s2:4, s3:4, s4:4)
#define ASTR  168            // LDS act row stride in ushorts (336 B = 21*16)
#define WLDSB (NTILE * 64 * 16)        // 28672 B weight frags
#define ALDSB (64 * ASTR * 2)          // 21504 B activations
// K-REORDER: k' = 0..63 -> x (w2), k' = 64..130 -> xc (w1), 131..159 zero.
// cmb row: 128 bf16 = [proj x64 | xp x64] = 256 B
// cmb layout: per batch b, row r at (b*NP1 + r); r=0 is the sentinel row
// [-inf x64 | 0 x64] so gather can use ik+1 unconditionally (no clamp/mask).

typedef float f32x4 __attribute__((ext_vector_type(4)));
typedef short s16x8 __attribute__((ext_vector_type(8)));

static __device__ __forceinline__ unsigned short f2bf(float f) {
    unsigned int u = __float_as_uint(f);
    u = (u + 0x7fffu + ((u >> 16) & 1u)) >> 16;   // RNE
    return (unsigned short)u;
}
static __device__ __forceinline__ float bf2f(unsigned short h) {
    return __uint_as_float((unsigned int)h << 16);
}
static __device__ __forceinline__ unsigned int pack2(float a, float b) {
    return (unsigned int)f2bf(a) | ((unsigned int)f2bf(b) << 16);
}

// ---------------------------------------------------------------------------
// Kernel 1: projection via MFMA 16x16x32 bf16, integrated weight-frag build.
// Frag layout (unchanged from r9/r13): chunk = tile*64 + (q*16+m); element
// j = W[k'=s*32+q*8+j][c=nt*16+m]; tiles 0..15: s=tile>>3, nt=tile&7 (x/w2,
// proj cols ux-scaled, xp cols raw); tiles 16..27: s=2+((tile-16)>>2),
// nt=(tile-16)&3 (xc/w1 part, proj cols only).
// NEW this round: w1 s=2,3 chunks are contiguous 8-float runs of a w1 row,
// so they are built with vectorized float4 loads + ds_write_b128 (like w2)
// instead of the per-element magic-div scatter; only k'=128..130 (3 floats
// per c) is scalar. Same restructure for the xc activation staging.
// ---------------------------------------------------------------------------
__global__ __launch_bounds__(256) void proj_kernel(
    const float* __restrict__ x, const float* __restrict__ xcm,
    const float* __restrict__ w1, const float* __restrict__ w2,
    const float* __restrict__ bias, const int* __restrict__ use_x_p,
    unsigned short* __restrict__ cmb)
{
    __shared__ char smem[WLDSB + ALDSB];      // 50176 B -> 3 blocks/CU
    uint4* ldsb          = (uint4*)smem;                    // frag chunks
    unsigned short* lwb  = (unsigned short*)smem;           // frag region, b16 view
    unsigned short* lact = (unsigned short*)(smem + WLDSB); // activations
    unsigned int*  ldsd  = (unsigned int*)lact;

    const int t    = threadIdx.x;
    // XCD swizzle: xcd g computes batches 2g,2g+1 (matches gather's reader slab)
    const int row0 = (blockIdx.x & 7) * (ROWS_ / 8) + (blockIdx.x >> 3) * 64;
    const int ux   = use_x_p[0];
    const int bb   = row0 >> 12;              // batch index

    // ---- sentinel row for this batch (one block per batch writes it):
    // proj half = bf16 -inf (0xff80), xp half = 0 ----
    if ((row0 & (N_ - 1)) == 0 && t < 16) {
        uint4* sp = (uint4*)(cmb + (size_t)bb * NP1 * NCH);
        sp[t] = (t < 8)
            ? make_uint4(0xff80ff80u, 0xff80ff80u, 0xff80ff80u, 0xff80ff80u)
            : make_uint4(0u, 0u, 0u, 0u);
    }

    // ---- phase 0: pre-zero the s=4 tiles (chunks 1536..1791, 4 KB) so the
    // w1 tail only needs to fill k'=128..130 ----
    ldsb[1536 + t] = make_uint4(0u, 0u, 0u, 0u);
    __syncthreads();

    // ---- w2 -> s{0,1} frag chunks: 512 chunks, 2 per thread. One aligned
    // 8-float row chunk == one frag chunk. ----
#pragma unroll
    for (int it = 0; it < 2; ++it) {
        const int wid = it * 256 + t;              // 0..511
        const int c   = wid >> 3, kc = wid & 7;    // kc -> (s,q)
        const int s   = kc >> 2,  q  = kc & 3;
        const float4 v0 = *(const float4*)(w2 + c * DIN_ + kc * 8);
        const float4 v1 = *(const float4*)(w2 + c * DIN_ + kc * 8 + 4);
        uint4 pk;
        pk.x = pack2(v0.x, v0.y); pk.y = pack2(v0.z, v0.w);
        pk.z = pack2(v1.x, v1.y); pk.w = pack2(v1.z, v1.w);
        const int lane = q * 16 + (c & 15);
        ldsb[(s * 8 + 4 + (c >> 4)) * 64 + lane] = pk;                   // xp col
        ldsb[(s * 8 + (c >> 4)) * 64 + lane] =
            ux ? pk : make_uint4(0u, 0u, 0u, 0u);                        // proj col
    }

    // ---- w1 -> s{2,3} frag chunks (tiles 16..23): 512 chunks, 2 per thread.
    // Chunk (t16, l=q*16+m) = w1[c = (t16&3)*16+m][db = (t16>>2)*32 + q*8 .. +7]
    // — contiguous floats, 4-B aligned. ----
#pragma unroll
    for (int it = 0; it < 2; ++it) {
        const int wid = it * 256 + t;              // 0..511
        const int t16 = wid >> 6;                  // tile-16: 0..7
        const int l   = wid & 63;
        const int q   = l >> 4, m = l & 15;
        const int c   = (t16 & 3) * 16 + m;
        const int db  = ((t16 >> 2) << 5) + q * 8; // 0..56
        const float* wp = w1 + c * DINC_ + db;     // max idx 63*67+63 < 4288
        const float4 v0 = *(const float4*)(wp);
        const float4 v1 = *(const float4*)(wp + 4);
        uint4 pk;
        pk.x = pack2(v0.x, v0.y); pk.y = pack2(v0.z, v0.w);
        pk.z = pack2(v1.x, v1.y); pk.w = pack2(v1.z, v1.w);
        ldsb[(16 + t16) * 64 + l] = pk;
    }
    // ---- w1 tail k'=128..130 -> s=4 tiles (24..27), q=0 lanes, j=0..2 ----
    if (t < 64) {
        const int c     = t;                       // c = (t>>4)*16 + (t&15)
        const int chunk = (24 + (t >> 4)) * 64 + (t & 15);
        const float* wr = w1 + c * DINC_ + 64;     // cols 64..66, in-bounds
        lwb[chunk * 8 + 0] = f2bf(wr[0]);
        lwb[chunk * 8 + 1] = f2bf(wr[1]);
        lwb[chunk * 8 + 2] = f2bf(wr[2]);
    }

    // ---- x activations: 1024 aligned float4, 4 per thread ----
    {
        const float4* sx4 = (const float4*)(x + (size_t)row0 * DIN_);
#pragma unroll
        for (int j = 0; j < 4; ++j) {
            const int idx = j * 256 + t;           // 0..1023
            const float4 v = sx4[idx];
            const int row = idx >> 4, f4 = idx & 15;
            *(uint2*)(ldsd + row * 84 + f4 * 2) =
                make_uint2(pack2(v.x, v.y), pack2(v.z, v.w));
        }
    }
    // ---- xc activations: vectorized [row][dg*8..+7] chunks (512, 2/thread),
    // then the 3-float row tail d=64..66 (+ zero at 131) ----
#pragma unroll
    for (int it = 0; it < 2; ++it) {
        const int wid = it * 256 + t;              // 0..511
        const int row = wid >> 3, dg = wid & 7;
        const float* sp = xcm + (size_t)(row0 + row) * DINC_ + dg * 8;
        const float4 v0 = *(const float4*)(sp);
        const float4 v1 = *(const float4*)(sp + 4);
        uint4 pk;
        pk.x = pack2(v0.x, v0.y); pk.y = pack2(v0.z, v0.w);
        pk.z = pack2(v1.x, v1.y); pk.w = pack2(v1.z, v1.w);
        *(uint4*)(lact + row * ASTR + 64 + dg * 8) = pk;   // 16-B aligned
    }
    if (t < 64) {
        const float* sp = xcm + (size_t)(row0 + t) * DINC_ + 64;
        unsigned short* dp = lact + t * ASTR + 128;
        dp[0] = f2bf(sp[0]); dp[1] = f2bf(sp[1]); dp[2] = f2bf(sp[2]); dp[3] = 0;
    }
    for (int i = t; i < 64 * 14; i += 256) {       // zero k'=132..159 pad
        const int row = i / 14, j2 = i - row * 14;
        ldsd[row * 84 + 66 + j2] = 0;
    }
    __syncthreads();

    const int l = t & 63;
    const int w = __builtin_amdgcn_readfirstlane(t >> 6);
    const int q = l >> 4, m = l & 15;

    const unsigned short* arow = lact + (w * 16 + m) * ASTR;
    s16x8 af[5];
#pragma unroll
    for (int s = 0; s < 5; ++s)
        af[s] = *(const s16x8*)(arow + s * 32 + q * 8);

    const s16x8* bfr = (const s16x8*)ldsb;

    f32x4 acc[8];
#pragma unroll
    for (int nt = 0; nt < 8; ++nt) acc[nt] = (f32x4){0.f, 0.f, 0.f, 0.f};

#pragma unroll
    for (int s = 0; s < 2; ++s)                  // full tiles: all 8 ntiles
#pragma unroll
        for (int nt = 0; nt < 8; ++nt)
            acc[nt] = __builtin_amdgcn_mfma_f32_16x16x32_bf16(
                bfr[(s * 8 + nt) * 64 + l], af[s], acc[nt], 0, 0, 0);
#pragma unroll
    for (int s = 2; s < 5; ++s)                  // proj-only tiles: ntiles 0..3
#pragma unroll
        for (int nt = 0; nt < 4; ++nt)
            acc[nt] = __builtin_amdgcn_mfma_f32_16x16x32_bf16(
                bfr[(16 + (s - 2) * 4 + nt) * 64 + l], af[s], acc[nt], 0, 0, 0);

    const int row_g = row0 + w * 16 + m;
    unsigned short* rowp = cmb + (size_t)(row_g + bb + 1) * NCH; // +sentinel offs
    const int chq = q * 4;
#pragma unroll
    for (int nt = 0; nt < 8; ++nt) {
        f32x4 a = acc[nt];
        if (nt < 4) {
            const float4 bv = *(const float4*)(bias + nt * 16 + chq);
            a[0] += bv.x; a[1] += bv.y; a[2] += bv.z; a[3] += bv.w;
        }
        *(uint2*)(rowp + nt * 16 + chq) =
            make_uint2(pack2(a[0], a[1]), pack2(a[2], a[3]));
    }
}

// ---------------------------------------------------------------------------
// Kernel 2: gather + masked max + center subtraction, 2 pairs per wave.
// NEW this round: -inf sentinel row removes the clamp + 2 cndmask per k;
// pure 32-bit in-slab offsets ((ik+1)<<8 + ln*4 < 1 MiB) -> saddr-form loads.
// ---------------------------------------------------------------------------
__global__ __launch_bounds__(256) void gather_max_kernel(
    const int* __restrict__ indexes, const unsigned short* __restrict__ cmb,
    const int* __restrict__ use_x_p, float* __restrict__ out)
{
    const int lane = threadIdx.x & 63;
    const int h    = lane >> 5;
    const int ln   = lane & 31;
    const int wv   = __builtin_amdgcn_readfirstlane(threadIdx.x >> 6);
    const int grp  = (blockIdx.x & 7) * 1024 + (blockIdx.x >> 3) * 4 + wv; // 8192 groups
    const int pairA = grp * 2;
    const int b     = grp >> 9;          // 512 groups per batch
    const int ux    = use_x_p[0];

    const int* iA = indexes + (size_t)pairA * K_;       // uniform -> s_load
    const int* iB = iA + K_;
    const char* cb = (const char*)cmb + (size_t)b * NP1 * 256;
    const unsigned lnoff = (unsigned)(ln << 2);

    const float NEG = -__builtin_inff();
    float m0 = NEG, m1 = NEG;
#pragma unroll
    for (int k = 0; k < K_; ++k) {
        const int ik = h ? iB[k] : iA[k];
        const unsigned off = ((unsigned)(ik + 1) << 8) + lnoff;
        const unsigned int v = *(const unsigned int*)(cb + off);
        m0 = fmaxf(m0, bf2f((unsigned short)(v & 0xffff)));
        m1 = fmaxf(m1, bf2f((unsigned short)(v >> 16)));
    }
    if (ux) {
        const int i0 = h ? iB[0] : iA[0];               // center, always valid
        const unsigned off0 = ((unsigned)(i0 + 1) << 8) + 128u + lnoff;
        const unsigned int c = *(const unsigned int*)(cb + off0);
        m0 -= bf2f((unsigned short)(c & 0xffff));
        m1 -= bf2f((unsigned short)(c >> 16));
    }
    const int pair = pairA + h;
    *(float2*)(out + (size_t)pair * 64 + ln * 2) = make_float2(m0, m1);
}

// ---------------------------------------------------------------------------
// Fallback (ws too small): fully fused, recomputes projections per gather.
// ---------------------------------------------------------------------------
__global__ __launch_bounds__(256, 1) void fused_fallback_kernel(
    const float* __restrict__ x, const float* __restrict__ xcm,
    const int* __restrict__ indexes,
    const float* __restrict__ w1, const float* __restrict__ w2,
    const float* __restrict__ bias, const int* __restrict__ use_x_p,
    float* __restrict__ out)
{
    const int lane = threadIdx.x & 63;
    const int pair = (blockIdx.x * blockDim.x + threadIdx.x) >> 6;
    const int b    = pair >> 10;
    const int ux   = use_x_p[0];

    float W1[DINC_];
#pragma unroll
    for (int j = 0; j < DINC_; ++j) W1[j] = w1[lane * DINC_ + j];
    float W2[DIN_];
#pragma unroll
    for (int j = 0; j < DIN_; ++j) W2[j] = w2[lane * DIN_ + j];
    const float bv = bias[lane];

    const int* idxp  = indexes + (size_t)pair * K_;
    const int  myidx = idxp[lane & 31];

    const float NEG = -__builtin_inff();
    float m = NEG;
    for (int k = 0; k < K_; ++k) {
        const int ik = __shfl(myidx, k, 64);
        if (ik < 0) continue;
        const float* xc_row = xcm + ((size_t)b * N_ + ik) * DINC_;
        float a1 = bv;
#pragma unroll
        for (int j = 0; j < DINC_; ++j) a1 += xc_row[j] * W1[j];
        if (ux) {
            const float* x_row = x + ((size_t)b * N_ + ik) * DIN_;
            float a2 = 0.f;
#pragma unroll
            for (int j = 0; j < DIN_; ++j) a2 += x_row[j] * W2[j];
            a1 += a2;
        }
        m = fmaxf(m, a1);
    }
    if (ux) {
        const int i0 = __shfl(myidx, 0, 64);
        const float* x_row = x + ((size_t)b * N_ + i0) * DIN_;
        float a2 = 0.f;
#pragma unroll
        for (int j = 0; j < DIN_; ++j) a2 += x_row[j] * W2[j];
        m -= a2;
    }
    out[(size_t)pair * DOUT_ + lane] = m;
}

extern "C" void kernel_launch(void* const* d_in, const int* in_sizes, int n_in,
                              void* d_out, int out_size, void* d_ws, size_t ws_size,
                              hipStream_t stream)
{
    const float* x    = (const float*)d_in[0];
    const float* xcm  = (const float*)d_in[1];
    const int*   idx  = (const int*)d_in[2];
    const float* w1   = (const float*)d_in[3];
    const float* w2   = (const float*)d_in[4];
    const float* bias = (const float*)d_in[5];
    const int*   ux   = (const int*)d_in[6];
    float* out = (float*)d_out;

    const size_t cmb_bytes =
        (size_t)(ROWS_ + B_) * NCH * sizeof(unsigned short);  // ~16.8 MiB
    const int npairs = B_ * S_;   // 16384

    if (ws_size >= cmb_bytes) {
        unsigned short* cmb = (unsigned short*)d_ws;
        proj_kernel<<<ROWS_ / 64, 256, 0, stream>>>(x, xcm, w1, w2, bias, ux, cmb);
        gather_max_kernel<<<(npairs / 2) / 4, 256, 0, stream>>>(idx, cmb, ux, out);
    } else {
        fused_fallback_kernel<<<npairs / 4, 256, 0, stream>>>(x, xcm, idx, w1, w2,
                                                              bias, ux, out);
    }
}

// Round 2
// 98.962 us; speedup vs baseline: 1.0531x; 1.0157x over previous
//
#include <hip/hip_runtime.h>

#define B_    16
#define N_    4096
#define S_    1024
#define K_    32
#define DIN_  64
#define DINC_ 67
#define DOUT_ 64
#define ROWS_ (B_ * N_)
#define NCH   128            // 64 proj + 64 xp output columns
#define NP1   (N_ + 1)       // cmb rows per batch: sentinel row 0 + N rows
#define NTILE 28             // nonzero weight tiles (s0:8, s1:8, s2:4, s3:4, s4:4)
#define ASTR  168            // LDS act row stride in ushorts (336 B = 21*16)
#define WLDSB (NTILE * 64 * 16)        // 28672 B weight frags
#define ALDSB (64 * ASTR * 2)          // 21504 B activations
// K-REORDER: k' = 0..63 -> x (w2), k' = 64..130 -> xc (w1), 131..159 zero.
// cmb row: 128 bf16 = [proj x64 | xp x64] = 256 B
// cmb layout: per batch b, row r at (b*NP1 + r); r=0 is the sentinel row
// [-inf x64 | 0 x64] so gather can use ik+1 unconditionally (no clamp/mask).

typedef float f32x4 __attribute__((ext_vector_type(4)));
typedef short s16x8 __attribute__((ext_vector_type(8)));

static __device__ __forceinline__ unsigned short f2bf(float f) {
    unsigned int u = __float_as_uint(f);
    u = (u + 0x7fffu + ((u >> 16) & 1u)) >> 16;   // RNE
    return (unsigned short)u;
}
static __device__ __forceinline__ float bf2f(unsigned short h) {
    return __uint_as_float((unsigned int)h << 16);
}
static __device__ __forceinline__ unsigned int pack2(float a, float b) {
    return (unsigned int)f2bf(a) | ((unsigned int)f2bf(b) << 16);
}
static __device__ __forceinline__ float bflo(unsigned int u) {
    return __uint_as_float(u << 16);
}
static __device__ __forceinline__ float bfhi(unsigned int u) {
    return __uint_as_float(u & 0xffff0000u);
}

// ---------------------------------------------------------------------------
// Kernel 1: projection via MFMA 16x16x32 bf16, integrated weight-frag build.
// (unchanged from round-1 best: at its ~8 µs memory floor — 33 MB read +
// 17 MB cmb write at ~6.3 TB/s; staging VALU fully vectorized.)
// ---------------------------------------------------------------------------
__global__ __launch_bounds__(256) void proj_kernel(
    const float* __restrict__ x, const float* __restrict__ xcm,
    const float* __restrict__ w1, const float* __restrict__ w2,
    const float* __restrict__ bias, const int* __restrict__ use_x_p,
    unsigned short* __restrict__ cmb)
{
    __shared__ char smem[WLDSB + ALDSB];      // 50176 B -> 3 blocks/CU
    uint4* ldsb          = (uint4*)smem;                    // frag chunks
    unsigned short* lwb  = (unsigned short*)smem;           // frag region, b16 view
    unsigned short* lact = (unsigned short*)(smem + WLDSB); // activations
    unsigned int*  ldsd  = (unsigned int*)lact;

    const int t    = threadIdx.x;
    // XCD swizzle: xcd g computes batches 2g,2g+1 (matches gather's reader slab)
    const int row0 = (blockIdx.x & 7) * (ROWS_ / 8) + (blockIdx.x >> 3) * 64;
    const int ux   = use_x_p[0];
    const int bb   = row0 >> 12;              // batch index

    // ---- sentinel row for this batch (one block per batch writes it):
    // proj half = bf16 -inf (0xff80), xp half = 0 ----
    if ((row0 & (N_ - 1)) == 0 && t < 16) {
        uint4* sp = (uint4*)(cmb + (size_t)bb * NP1 * NCH);
        sp[t] = (t < 8)
            ? make_uint4(0xff80ff80u, 0xff80ff80u, 0xff80ff80u, 0xff80ff80u)
            : make_uint4(0u, 0u, 0u, 0u);
    }

    // ---- phase 0: pre-zero the s=4 tiles (chunks 1536..1791, 4 KB) so the
    // w1 tail only needs to fill k'=128..130 ----
    ldsb[1536 + t] = make_uint4(0u, 0u, 0u, 0u);
    __syncthreads();

    // ---- w2 -> s{0,1} frag chunks: 512 chunks, 2 per thread. One aligned
    // 8-float row chunk == one frag chunk. ----
#pragma unroll
    for (int it = 0; it < 2; ++it) {
        const int wid = it * 256 + t;              // 0..511
        const int c   = wid >> 3, kc = wid & 7;    // kc -> (s,q)
        const int s   = kc >> 2,  q  = kc & 3;
        const float4 v0 = *(const float4*)(w2 + c * DIN_ + kc * 8);
        const float4 v1 = *(const float4*)(w2 + c * DIN_ + kc * 8 + 4);
        uint4 pk;
        pk.x = pack2(v0.x, v0.y); pk.y = pack2(v0.z, v0.w);
        pk.z = pack2(v1.x, v1.y); pk.w = pack2(v1.z, v1.w);
        const int lane = q * 16 + (c & 15);
        ldsb[(s * 8 + 4 + (c >> 4)) * 64 + lane] = pk;                   // xp col
        ldsb[(s * 8 + (c >> 4)) * 64 + lane] =
            ux ? pk : make_uint4(0u, 0u, 0u, 0u);                        // proj col
    }

    // ---- w1 -> s{2,3} frag chunks (tiles 16..23): 512 chunks, 2 per thread.
    // Chunk (t16, l=q*16+m) = w1[c = (t16&3)*16+m][db = (t16>>2)*32 + q*8 .. +7]
    // — contiguous floats, 4-B aligned. ----
#pragma unroll
    for (int it = 0; it < 2; ++it) {
        const int wid = it * 256 + t;              // 0..511
        const int t16 = wid >> 6;                  // tile-16: 0..7
        const int l   = wid & 63;
        const int q   = l >> 4, m = l & 15;
        const int c   = (t16 & 3) * 16 + m;
        const int db  = ((t16 >> 2) << 5) + q * 8; // 0..56
        const float* wp = w1 + c * DINC_ + db;     // max idx 63*67+63 < 4288
        const float4 v0 = *(const float4*)(wp);
        const float4 v1 = *(const float4*)(wp + 4);
        uint4 pk;
        pk.x = pack2(v0.x, v0.y); pk.y = pack2(v0.z, v0.w);
        pk.z = pack2(v1.x, v1.y); pk.w = pack2(v1.z, v1.w);
        ldsb[(16 + t16) * 64 + l] = pk;
    }
    // ---- w1 tail k'=128..130 -> s=4 tiles (24..27), q=0 lanes, j=0..2 ----
    if (t < 64) {
        const int c     = t;                       // c = (t>>4)*16 + (t&15)
        const int chunk = (24 + (t >> 4)) * 64 + (t & 15);
        const float* wr = w1 + c * DINC_ + 64;     // cols 64..66, in-bounds
        lwb[chunk * 8 + 0] = f2bf(wr[0]);
        lwb[chunk * 8 + 1] = f2bf(wr[1]);
        lwb[chunk * 8 + 2] = f2bf(wr[2]);
    }

    // ---- x activations: 1024 aligned float4, 4 per thread ----
    {
        const float4* sx4 = (const float4*)(x + (size_t)row0 * DIN_);
#pragma unroll
        for (int j = 0; j < 4; ++j) {
            const int idx = j * 256 + t;           // 0..1023
            const float4 v = sx4[idx];
            const int row = idx >> 4, f4 = idx & 15;
            *(uint2*)(ldsd + row * 84 + f4 * 2) =
                make_uint2(pack2(v.x, v.y), pack2(v.z, v.w));
        }
    }
    // ---- xc activations: vectorized [row][dg*8..+7] chunks (512, 2/thread),
    // then the 3-float row tail d=64..66 (+ zero at 131) ----
#pragma unroll
    for (int it = 0; it < 2; ++it) {
        const int wid = it * 256 + t;              // 0..511
        const int row = wid >> 3, dg = wid & 7;
        const float* sp = xcm + (size_t)(row0 + row) * DINC_ + dg * 8;
        const float4 v0 = *(const float4*)(sp);
        const float4 v1 = *(const float4*)(sp + 4);
        uint4 pk;
        pk.x = pack2(v0.x, v0.y); pk.y = pack2(v0.z, v0.w);
        pk.z = pack2(v1.x, v1.y); pk.w = pack2(v1.z, v1.w);
        *(uint4*)(lact + row * ASTR + 64 + dg * 8) = pk;   // 16-B aligned
    }
    if (t < 64) {
        const float* sp = xcm + (size_t)(row0 + t) * DINC_ + 64;
        unsigned short* dp = lact + t * ASTR + 128;
        dp[0] = f2bf(sp[0]); dp[1] = f2bf(sp[1]); dp[2] = f2bf(sp[2]); dp[3] = 0;
    }
    for (int i = t; i < 64 * 14; i += 256) {       // zero k'=132..159 pad
        const int row = i / 14, j2 = i - row * 14;
        ldsd[row * 84 + 66 + j2] = 0;
    }
    __syncthreads();

    const int l = t & 63;
    const int w = __builtin_amdgcn_readfirstlane(t >> 6);
    const int q = l >> 4, m = l & 15;

    const unsigned short* arow = lact + (w * 16 + m) * ASTR;
    s16x8 af[5];
#pragma unroll
    for (int s = 0; s < 5; ++s)
        af[s] = *(const s16x8*)(arow + s * 32 + q * 8);

    const s16x8* bfr = (const s16x8*)ldsb;

    f32x4 acc[8];
#pragma unroll
    for (int nt = 0; nt < 8; ++nt) acc[nt] = (f32x4){0.f, 0.f, 0.f, 0.f};

#pragma unroll
    for (int s = 0; s < 2; ++s)                  // full tiles: all 8 ntiles
#pragma unroll
        for (int nt = 0; nt < 8; ++nt)
            acc[nt] = __builtin_amdgcn_mfma_f32_16x16x32_bf16(
                bfr[(s * 8 + nt) * 64 + l], af[s], acc[nt], 0, 0, 0);
#pragma unroll
    for (int s = 2; s < 5; ++s)                  // proj-only tiles: ntiles 0..3
#pragma unroll
        for (int nt = 0; nt < 4; ++nt)
            acc[nt] = __builtin_amdgcn_mfma_f32_16x16x32_bf16(
                bfr[(16 + (s - 2) * 4 + nt) * 64 + l], af[s], acc[nt], 0, 0, 0);

    const int row_g = row0 + w * 16 + m;
    unsigned short* rowp = cmb + (size_t)(row_g + bb + 1) * NCH; // +sentinel offs
    const int chq = q * 4;
#pragma unroll
    for (int nt = 0; nt < 8; ++nt) {
        f32x4 a = acc[nt];
        if (nt < 4) {
            const float4 bv = *(const float4*)(bias + nt * 16 + chq);
            a[0] += bv.x; a[1] += bv.y; a[2] += bv.z; a[3] += bv.w;
        }
        *(uint2*)(rowp + nt * 16 + chq) =
            make_uint2(pack2(a[0], a[1]), pack2(a[2], a[3]));
    }
}

// ---------------------------------------------------------------------------
// Kernel 2: gather + masked max + center subtraction.
// NEW this round: 8 pairs per wave. Lane = (pair-slot p = lane>>3) x
// (channel octet o = lane&7). Per k: one dwordx4 (16 B = 8 bf16 channels)
// + 8 unpack-and-fmax. All 32 indexes preloaded to registers (8x int4,
// fully unrolled -> static indexing). 4x fewer VMEM issues and 4x fewer
// waves than the 2-pair version; sentinel row still replaces all masking.
// ---------------------------------------------------------------------------
__global__ __launch_bounds__(256) void gather_max_kernel(
    const int* __restrict__ indexes, const unsigned short* __restrict__ cmb,
    const int* __restrict__ use_x_p, float* __restrict__ out)
{
    const int lane = threadIdx.x & 63;
    const int wv   = __builtin_amdgcn_readfirstlane(threadIdx.x >> 6);
    // 512 blocks: xcd g (blockIdx&7) handles batches 2g,2g+1 (matches proj slab)
    const int pairBase = (blockIdx.x & 7) * 2048 + (blockIdx.x >> 3) * 32 + wv * 8;
    const int pair = pairBase + (lane >> 3);        // 8 pairs per wave
    const int o    = lane & 7;                      // channel octet 0..7
    const int b    = pairBase >> 10;                // wave-uniform batch
    const int ux   = use_x_p[0];

    const char* cb = (const char*)cmb + (size_t)b * NP1 * 256;
    const unsigned chb = (unsigned)(o << 4);        // byte offset of octet

    // preload this pair's 32 indexes into registers (static after unroll)
    const int* ip = indexes + (size_t)pair * K_;
    int idxr[32];
#pragma unroll
    for (int kb = 0; kb < 8; ++kb) {
        const int4 v = *(const int4*)(ip + kb * 4);
        idxr[kb * 4 + 0] = v.x; idxr[kb * 4 + 1] = v.y;
        idxr[kb * 4 + 2] = v.z; idxr[kb * 4 + 3] = v.w;
    }

    const float NEG = -__builtin_inff();
    float m[8];
#pragma unroll
    for (int j = 0; j < 8; ++j) m[j] = NEG;

#pragma unroll
    for (int k = 0; k < K_; ++k) {
        const unsigned off = ((unsigned)(idxr[k] + 1) << 8) + chb;
        const uint4 v = *(const uint4*)(cb + off);
        m[0] = fmaxf(m[0], bflo(v.x)); m[1] = fmaxf(m[1], bfhi(v.x));
        m[2] = fmaxf(m[2], bflo(v.y)); m[3] = fmaxf(m[3], bfhi(v.y));
        m[4] = fmaxf(m[4], bflo(v.z)); m[5] = fmaxf(m[5], bfhi(v.z));
        m[6] = fmaxf(m[6], bflo(v.w)); m[7] = fmaxf(m[7], bfhi(v.w));
    }
    if (ux) {
        const unsigned off0 = ((unsigned)(idxr[0] + 1) << 8) + 128u + chb;
        const uint4 c = *(const uint4*)(cb + off0);
        m[0] -= bflo(c.x); m[1] -= bfhi(c.x);
        m[2] -= bflo(c.y); m[3] -= bfhi(c.y);
        m[4] -= bflo(c.z); m[5] -= bfhi(c.z);
        m[6] -= bflo(c.w); m[7] -= bfhi(c.w);
    }
    float* op = out + (size_t)pair * DOUT_ + o * 8;
    *(float4*)op       = make_float4(m[0], m[1], m[2], m[3]);
    *(float4*)(op + 4) = make_float4(m[4], m[5], m[6], m[7]);
}

// ---------------------------------------------------------------------------
// Fallback (ws too small): fully fused, recomputes projections per gather.
// ---------------------------------------------------------------------------
__global__ __launch_bounds__(256, 1) void fused_fallback_kernel(
    const float* __restrict__ x, const float* __restrict__ xcm,
    const int* __restrict__ indexes,
    const float* __restrict__ w1, const float* __restrict__ w2,
    const float* __restrict__ bias, const int* __restrict__ use_x_p,
    float* __restrict__ out)
{
    const int lane = threadIdx.x & 63;
    const int pair = (blockIdx.x * blockDim.x + threadIdx.x) >> 6;
    const int b    = pair >> 10;
    const int ux   = use_x_p[0];

    float W1[DINC_];
#pragma unroll
    for (int j = 0; j < DINC_; ++j) W1[j] = w1[lane * DINC_ + j];
    float W2[DIN_];
#pragma unroll
    for (int j = 0; j < DIN_; ++j) W2[j] = w2[lane * DIN_ + j];
    const float bv = bias[lane];

    const int* idxp  = indexes + (size_t)pair * K_;
    const int  myidx = idxp[lane & 31];

    const float NEG = -__builtin_inff();
    float m = NEG;
    for (int k = 0; k < K_; ++k) {
        const int ik = __shfl(myidx, k, 64);
        if (ik < 0) continue;
        const float* xc_row = xcm + ((size_t)b * N_ + ik) * DINC_;
        float a1 = bv;
#pragma unroll
        for (int j = 0; j < DINC_; ++j) a1 += xc_row[j] * W1[j];
        if (ux) {
            const float* x_row = x + ((size_t)b * N_ + ik) * DIN_;
            float a2 = 0.f;
#pragma unroll
            for (int j = 0; j < DIN_; ++j) a2 += x_row[j] * W2[j];
            a1 += a2;
        }
        m = fmaxf(m, a1);
    }
    if (ux) {
        const int i0 = __shfl(myidx, 0, 64);
        const float* x_row = x + ((size_t)b * N_ + i0) * DIN_;
        float a2 = 0.f;
#pragma unroll
        for (int j = 0; j < DIN_; ++j) a2 += x_row[j] * W2[j];
        m -= a2;
    }
    out[(size_t)pair * DOUT_ + lane] = m;
}

extern "C" void kernel_launch(void* const* d_in, const int* in_sizes, int n_in,
                              void* d_out, int out_size, void* d_ws, size_t ws_size,
                              hipStream_t stream)
{
    const float* x    = (const float*)d_in[0];
    const float* xcm  = (const float*)d_in[1];
    const int*   idx  = (const int*)d_in[2];
    const float* w1   = (const float*)d_in[3];
    const float* w2   = (const float*)d_in[4];
    const float* bias = (const float*)d_in[5];
    const int*   ux   = (const int*)d_in[6];
    float* out = (float*)d_out;

    const size_t cmb_bytes =
        (size_t)(ROWS_ + B_) * NCH * sizeof(unsigned short);  // ~16.8 MiB
    const int npairs = B_ * S_;   // 16384

    if (ws_size >= cmb_bytes) {
        unsigned short* cmb = (unsigned short*)d_ws;
        proj_kernel<<<ROWS_ / 64, 256, 0, stream>>>(x, xcm, w1, w2, bias, ux, cmb);
        // 16384 pairs / 8 per wave / 4 waves per block = 512 blocks
        gather_max_kernel<<<512, 256, 0, stream>>>(idx, cmb, ux, out);
    } else {
        fused_fallback_kernel<<<npairs / 4, 256, 0, stream>>>(x, xcm, idx, w1, w2,
                                                              bias, ux, out);
    }
}